// Round 7
// baseline (419.771 us; speedup 1.0000x reference)
//
#include <hip/hip_runtime.h>
#include <hip/hip_bf16.h>
#include <type_traits>

static constexpr int T = 2048;
static constexpr int B = 4;
static constexpr int D = 1024;
static constexpr int E = 2 * D;     // 2048
static constexpr int M1 = T * B;    // 8192

typedef __attribute__((ext_vector_type(8))) short short8;   // 8 bf16 = 4 VGPRs (MFMA A/B frag)
typedef __attribute__((ext_vector_type(4))) float f32x4;    // MFMA C/D frag

__device__ inline ushort f2bf(float x) {
    __hip_bfloat16 h = __float2bfloat16(x);
    return __builtin_bit_cast(ushort, h);
}

__device__ inline void glds16(const void* g, void* l) {
    __builtin_amdgcn_global_load_lds(
        (const __attribute__((address_space(1))) void*)g,
        (__attribute__((address_space(3))) void*)l, 16, 0, 0);
}

// XCD-aware bijective block swizzle for standalone gemm launches (PV/OP).
// HW assigns XCD = linear id % 8; remap so each XCD gets a contiguous
// bm-stripe (shared A-panels -> L2 reuse). Requires nx*ny % 8 == 0.
__device__ inline void xcd_swizzle(int nx, int ny, int& bn_i, int& bm_i) {
    int id = blockIdx.y * nx + blockIdx.x;
    const int q = (nx * ny) >> 3;            // ids per XCD chunk
    id = (id & 7) * q + (id >> 3);           // bijective chunking
    bm_i = id / nx;                          // contiguous bm per XCD
    bn_i = id - bm_i * nx;
}

// ===========================================================================
// 128x128-tile, BK=64, 4-wave 2-phase GEMM body (NT): proven structure.
//   C[m,n] = alpha * sum_k A[m,k]*Bt[n,k] + bias[n]
// LDS rows are 64 bf16 = 128B. XOR chunk swizzle: global 16B-chunk c of
// tile-row m lives at LDS chunk c ^ (m&7)  -> 2-way bank aliasing = free.
// Batch offsets applied by caller; bm/bn tile indices passed in.
// ===========================================================================
template <typename OT>
__device__ __forceinline__ void gemm_body(
    const ushort* __restrict__ A, const ushort* __restrict__ Bt,
    OT* __restrict__ C, const float* __restrict__ bias,
    int K, int lda, int ldb, int ldc, float alpha, int bm, int bn)
{
    __shared__ ushort As[128 * 64];   // 16KB
    __shared__ ushort Bs[128 * 64];   // 16KB

    const int tid  = threadIdx.x;
    const int lane = tid & 63;
    const int wave = tid >> 6;        // 0..3
    const int wm = (wave & 1) * 64;
    const int wn = (wave >> 1) * 64;

    f32x4 acc[4][4] = {};

    const int srow  = lane >> 3;                         // 0..7 within 8-row gang
    const int sElem = (((lane & 7) ^ (lane >> 3))) * 8;  // swizzled global elem offset
    const int rbase = ((lane >> 4) ^ (lane & 7)) * 8;    // kb=0 read chunk
    const int rxor4 = 4 * 8;                             // kb=1 flips bit2 of chunk

    for (int k0 = 0; k0 < K; k0 += 64) {
        __syncthreads();
#pragma unroll
        for (int j = 0; j < 4; ++j) {
            const int r = wave * 32 + j * 8;             // gang base row
            glds16(Bt + (long long)(bn + r + srow) * ldb + (k0 + sElem),
                   (void*)&Bs[r * 64]);
            glds16(A + (long long)(bm + r + srow) * lda + (k0 + sElem),
                   (void*)&As[r * 64]);
        }
        __syncthreads();

#pragma unroll
        for (int kb = 0; kb < 2; ++kb) {
            const int rElem = rbase ^ (kb ? rxor4 : 0);
            short8 af[4], bf[4];
#pragma unroll
            for (int i = 0; i < 4; ++i) {
                const int m = wm + i * 16 + (lane & 15);
                af[i] = *(const short8*)&As[m * 64 + rElem];
            }
#pragma unroll
            for (int j = 0; j < 4; ++j) {
                const int n = wn + j * 16 + (lane & 15);
                bf[j] = *(const short8*)&Bs[n * 64 + rElem];
            }
#pragma unroll
            for (int i = 0; i < 4; ++i)
#pragma unroll
                for (int j = 0; j < 4; ++j)
                    acc[i][j] = __builtin_amdgcn_mfma_f32_16x16x32_bf16(af[i], bf[j], acc[i][j], 0, 0, 0);
        }
    }

    // epilogue: C/D layout col=lane&15, row=(lane>>4)*4+r  [verified m89]
#pragma unroll
    for (int j = 0; j < 4; ++j) {
        const int col = bn + wn + j * 16 + (lane & 15);
        const float bv = bias ? bias[col] : 0.0f;
#pragma unroll
        for (int i = 0; i < 4; ++i) {
            const int row0 = bm + wm + i * 16 + ((lane >> 4) << 2);
#pragma unroll
            for (int r = 0; r < 4; ++r) {
                const float v = acc[i][j][r] * alpha + bv;
                if constexpr (std::is_same<OT, float>::value)
                    C[(long long)(row0 + r) * ldc + col] = v;
                else
                    C[(long long)(row0 + r) * ldc + col] = f2bf(v);
            }
        }
    }
}

// fp32 -> bf16 cast of one 1024-float block
__device__ __forceinline__ void cast_blk(const float* __restrict__ s,
                                         ushort* __restrict__ d, int blk) {
    const int i = blk * 256 + threadIdx.x;
    const float4 v = ((const float4*)s)[i];
    ushort4 o;
    o.x = f2bf(v.x); o.y = f2bf(v.y); o.z = f2bf(v.z); o.w = f2bf(v.w);
    ((ushort4*)d)[i] = o;
}

// vt[b][d][s] = kv[(s*B+b)*E + D + d]   (64x64 LDS tile transpose)
__device__ __forceinline__ void transpose_body(const ushort* __restrict__ kv,
                                               ushort* __restrict__ vt,
                                               int s0, int d0, int b) {
    __shared__ ushort tile[64][65];
    const int t = threadIdx.x;
    const int dl = (t & 15) * 4, sl = t >> 4;
#pragma unroll
    for (int p = 0; p < 4; ++p) {
        const int s = sl + p * 16;
        const ushort4 v = *(const ushort4*)&kv[((long long)(s0 + s) * B + b) * E + D + d0 + dl];
        tile[s][dl + 0] = v.x; tile[s][dl + 1] = v.y;
        tile[s][dl + 2] = v.z; tile[s][dl + 3] = v.w;
    }
    __syncthreads();
    const int dl2 = t >> 4, sl2 = (t & 15) * 4;
#pragma unroll
    for (int p = 0; p < 4; ++p) {
        const int d = dl2 + p * 16;
        ushort4 o;
        o.x = tile[sl2 + 0][d]; o.y = tile[sl2 + 1][d];
        o.z = tile[sl2 + 2][d]; o.w = tile[sl2 + 3][d];
        *(ushort4*)&vt[(long long)b * D * T + (long long)(d0 + d) * T + s0 + sl2] = o;
    }
}

// Interleave decode shared by merged kernels. First 2048 linear ids
// alternate GROUPS OF 8 (primary-8, freeloader-8, ...): groups of 8 keep
// every XCD (id%8) serving both roles, and co-resident CUs host ~2-3
// gemm + ~2 freeloader blocks so freeloader BW hides under gemm latency.
// Remaining ids are all freeloaders.
//   primary  sub-ids: 0..1023   (requires exactly 1024 primary blocks)
//   freeload sub-ids: 0..(total-1024-1)
__device__ __forceinline__ bool interleave_decode(int id, int& sub) {
    if (id < 2048) {
        const int grp = id >> 3, w = id & 7;
        sub = (grp >> 1) * 8 + w;
        return (grp & 1) == 0;          // even groups = primary (gemm)
    }
    sub = 1024 + (id - 2048);
    return false;
}

// gemm sub-id g sits at linear id 16*(g>>3)+(g&7) -> XCD = g&7.
// tile = (g&7)*128 + (g>>3): each XCD owns a contiguous 128-tile stripe
// (8 bm rows), preserving A-panel L2 reuse per XCD.
__device__ __forceinline__ int gemm_tile_of(int g) {
    return (g & 7) * 128 + (g >> 3);
}

// ---------------------------------------------------------------------------
// Launch 1: cast x (8192 blocks) and w_in (2048 blocks) — the only inputs G1
// needs. q / w_out casts ride inside the G1 launch (launch 2).
// ---------------------------------------------------------------------------
__global__ __launch_bounds__(256) void cast_xw(
    const float* __restrict__ x, ushort* __restrict__ xbf,
    const float* __restrict__ w_in, ushort* __restrict__ wibf)
{
    const int blk = blockIdx.x;
    if (blk < 8192) cast_blk(x, xbf, blk);
    else            cast_blk(w_in, wibf, blk - 8192);
}

// ---------------------------------------------------------------------------
// Launch 2: G1 (kv = X.Win^T + b_in, 1024 gemm blocks) interleaved with
// freeloaders: q cast (8192) + w_out cast (1024). 1D grid 10240.
// ---------------------------------------------------------------------------
__global__ __launch_bounds__(256) void g1_cast(
    const ushort* __restrict__ xbf, const ushort* __restrict__ wibf,
    ushort* __restrict__ kv, const float* __restrict__ b_in,
    const float* __restrict__ query, ushort* __restrict__ qbf,
    const float* __restrict__ w_out, ushort* __restrict__ wobf)
{
    int sub;
    if (interleave_decode(blockIdx.x, sub)) {
        const int tile = gemm_tile_of(sub);            // 0..1023
        gemm_body<ushort>(xbf, wibf, kv, b_in, D, D, D, E, 1.0f,
                          (tile >> 4) * 128, (tile & 15) * 128);
    } else {
        if (sub < 8192) cast_blk(query, qbf, sub);     // 0..9215 total
        else            cast_blk(w_out, wobf, sub - 8192);
    }
}

// ---------------------------------------------------------------------------
// Launch 3: QK logits (1024 gemm blocks: 256 tiles x 4 batches) interleaved
// with transpose_v freeloaders (2048 blocks: 512 x 4 batches). 1D grid 3072.
// ---------------------------------------------------------------------------
__global__ __launch_bounds__(256) void qk_trans(
    const ushort* __restrict__ qbf, const ushort* __restrict__ kv,
    float* __restrict__ out_w, ushort* __restrict__ vt)
{
    int sub;
    if (interleave_decode(blockIdx.x, sub)) {
        const int tile = gemm_tile_of(sub);            // 0..1023
        const int b = tile >> 8, t = tile & 255;       // 4 batches x 256 tiles
        gemm_body<float>(qbf + (long long)b * D, kv + (long long)b * E,
                         out_w + (long long)b * T * T, nullptr,
                         D, B * D, B * E, T, 0.03125f,
                         (t >> 4) * 128, (t & 15) * 128);
    } else {
        const int b = sub >> 9, idx = sub & 511;       // 0..2047 total
        transpose_body(kv, vt, (idx & 31) * 64, (idx >> 5) * 64, b);
    }
}

// plain gemm wrapper for PV / out_proj
template <typename OT>
__global__ __launch_bounds__(256) void mfma_gemm_nt(
    const ushort* __restrict__ A, const ushort* __restrict__ Bt,
    OT* __restrict__ C, const float* __restrict__ bias,
    int K, int lda, int ldb, int ldc,
    long long aBatch, long long bBatch, long long cBatch, float alpha)
{
    int bn_i, bm_i;
    xcd_swizzle(gridDim.x, gridDim.y, bn_i, bm_i);
    gemm_body<OT>(A + blockIdx.z * aBatch, Bt + blockIdx.z * bBatch,
                  C + blockIdx.z * cBatch, bias,
                  K, lda, ldb, ldc, alpha, bm_i * 128, bn_i * 128);
}

// in-place fp32 softmax over rows of length T=2048, one 256-thr block per row.
// Also emits a bf16 copy of the row into Pbf for the PV GEMM.
__global__ __launch_bounds__(256) void softmax_kernel(float* __restrict__ W,
                                                      ushort* __restrict__ Pbf)
{
    const long long row = blockIdx.x;
    float* p = W + row * (long long)T;
    ushort* pb = Pbf + row * (long long)T;
    const int tid = threadIdx.x;

    float4 v0 = ((const float4*)p)[tid];
    float4 v1 = ((const float4*)p)[tid + 256];

    float m = fmaxf(fmaxf(fmaxf(v0.x, v0.y), fmaxf(v0.z, v0.w)),
                    fmaxf(fmaxf(v1.x, v1.y), fmaxf(v1.z, v1.w)));
#pragma unroll
    for (int off = 1; off < 64; off <<= 1) m = fmaxf(m, __shfl_xor(m, off));

    __shared__ float red[4];
    const int wid = tid >> 6, lane = tid & 63;
    if (lane == 0) red[wid] = m;
    __syncthreads();
    m = fmaxf(fmaxf(red[0], red[1]), fmaxf(red[2], red[3]));
    __syncthreads();

    v0.x = expf(v0.x - m); v0.y = expf(v0.y - m);
    v0.z = expf(v0.z - m); v0.w = expf(v0.w - m);
    v1.x = expf(v1.x - m); v1.y = expf(v1.y - m);
    v1.z = expf(v1.z - m); v1.w = expf(v1.w - m);

    float s = v0.x + v0.y + v0.z + v0.w + v1.x + v1.y + v1.z + v1.w;
#pragma unroll
    for (int off = 1; off < 64; off <<= 1) s += __shfl_xor(s, off);
    if (lane == 0) red[wid] = s;
    __syncthreads();
    s = red[0] + red[1] + red[2] + red[3];

    const float inv = 1.0f / s;
    v0.x *= inv; v0.y *= inv; v0.z *= inv; v0.w *= inv;
    v1.x *= inv; v1.y *= inv; v1.z *= inv; v1.w *= inv;

    ((float4*)p)[tid] = v0;
    ((float4*)p)[tid + 256] = v1;

    ushort4 o0, o1;
    o0.x = f2bf(v0.x); o0.y = f2bf(v0.y); o0.z = f2bf(v0.z); o0.w = f2bf(v0.w);
    o1.x = f2bf(v1.x); o1.y = f2bf(v1.y); o1.z = f2bf(v1.z); o1.w = f2bf(v1.w);
    ((ushort4*)pb)[tid] = o0;
    ((ushort4*)pb)[tid + 256] = o1;
}

extern "C" void kernel_launch(void* const* d_in, const int* in_sizes, int n_in,
                              void* d_out, int out_size, void* d_ws, size_t ws_size,
                              hipStream_t stream)
{
    const float* query = (const float*)d_in[0];   // (T,B,D)
    const float* x     = (const float*)d_in[1];   // (T,B,D)
    const float* w_in  = (const float*)d_in[2];   // (2D,D)
    const float* b_in  = (const float*)d_in[3];   // (2D,)
    const float* w_out = (const float*)d_in[4];   // (D,D)
    const float* b_out = (const float*)d_in[5];   // (D,)

    float* out_attn = (float*)d_out;                      // (T,B,D) fp32
    float* out_w    = out_attn + (long long)T * B * D;    // (B,T,T) fp32

    // workspace layout (unchanged):
    //  [0,16)   xbf (cast->GEMM1)         then amid (PV->out_proj)
    //  [16,32)  qbf (cast->QK)
    //  [32,36)  wibf   [36,38) wobf
    //  [38,70)  kv (GEMM1->QK/transpose)  then Pbf (softmax->PV)
    //  [70,86)  vt (transpose->PV)
    char* ws = (char*)d_ws;
    ushort* xbf  = (ushort*)(ws);
    ushort* amid = (ushort*)(ws);
    ushort* qbf  = (ushort*)(ws + (16ll << 20));
    ushort* wibf = (ushort*)(ws + (32ll << 20));
    ushort* wobf = (ushort*)(ws + (36ll << 20));
    ushort* kv   = (ushort*)(ws + (38ll << 20));
    ushort* Pbf  = (ushort*)(ws + (38ll << 20));
    ushort* vt   = (ushort*)(ws + (70ll << 20));

    // 1) cast x + w_in (only inputs G1 needs)
    cast_xw<<<dim3(8192 + 2048), 256, 0, stream>>>(x, xbf, w_in, wibf);

    // 2) kv = X.Win^T + b_in (1024 gemm blocks) interleaved w/ q,w_out casts
    g1_cast<<<dim3(10240), 256, 0, stream>>>(
        xbf, wibf, kv, b_in, query, qbf, w_out, wobf);

    // 3) logits = (1/32) q.k (1024 gemm blocks) interleaved w/ transpose_v
    qk_trans<<<dim3(3072), 256, 0, stream>>>(qbf, kv, out_w, vt);

    // 4) softmax rows in-place (output 1) + bf16 copy into Pbf
    softmax_kernel<<<dim3(B * T), 256, 0, stream>>>(out_w, Pbf);

    // 5) amid[t,b,d] = P . vt^T      M=2048 N=1024 K=2048, batch B   (8x16x4)
    mfma_gemm_nt<ushort><<<dim3(D / 128, T / 128, B), 256, 0, stream>>>(
        Pbf, vt, amid, nullptr, T, T, T, B * D,
        (long long)T * T, (long long)D * T, (long long)D, 1.0f);

    // 6) out = amid . Wout^T + b_out  M=8192 N=1024 K=1024   (8x64)
    mfma_gemm_nt<float><<<dim3(D / 128, M1 / 128, 1), 256, 0, stream>>>(
        amid, wobf, out_attn, b_out, D, D, D, D, 0, 0, 0, 1.0f);
}